// Round 1
// baseline (348.963 us; speedup 1.0000x reference)
//
#include <hip/hip_runtime.h>

// InteractionBlock: N=10000 nodes, E=320000 edges, C=64, A=4, NB=8, H=8.
// Pipeline (all on `stream`):
//   memset cnt -> k_hist -> k_scan -> k_scatter   (CSR by dst, rebuilt every call)
//   k_h        : h = (softplus(ee@Wfc1/sqrt8) - ln2)/sqrt8      -> ws
//   k_node_pre : y rows (lin1, /8) -> ws ; sc rows (/16) -> out
//   k_agg      : per-node gather over CSR edges, w recomputed from h & Wfc2(LDS),
//                LDS exchange, out += (agg @ Wlin2) / 64

__global__ __launch_bounds__(256) void k_hist(const int* __restrict__ ei,
                                              int* __restrict__ cnt, int nedges) {
  int e = blockIdx.x * 256 + threadIdx.x;
  if (e < nedges) atomicAdd(&cnt[ei[e]], 1);  // ei row 0 = dst
}

__global__ __launch_bounds__(1024) void k_scan(const int* __restrict__ cnt,
                                               int* __restrict__ offs,
                                               int* __restrict__ cur,
                                               int nnodes, int nedges) {
  // single block, handles nnodes <= 16384
  __shared__ int s[1024];
  const int tid = threadIdx.x;
  int vals[16];
  int tot = 0;
  const int start = tid * 16;
#pragma unroll
  for (int k = 0; k < 16; ++k) {
    int i = start + k;
    int c = (i < nnodes) ? cnt[i] : 0;
    vals[k] = c;
    tot += c;
  }
  s[tid] = tot;
  __syncthreads();
  for (int off = 1; off < 1024; off <<= 1) {
    int v = (tid >= off) ? s[tid - off] : 0;
    __syncthreads();
    s[tid] += v;
    __syncthreads();
  }
  int run = s[tid] - tot;  // exclusive prefix
#pragma unroll
  for (int k = 0; k < 16; ++k) {
    int i = start + k;
    if (i < nnodes) {
      offs[i] = run;
      cur[i] = run;
      run += vals[k];
    }
  }
  if (tid == 0) offs[nnodes] = nedges;
}

__global__ __launch_bounds__(256) void k_scatter(const int* __restrict__ ei,
                                                 int* __restrict__ cur,
                                                 int* __restrict__ eids, int nedges) {
  int e = blockIdx.x * 256 + threadIdx.x;
  if (e < nedges) {
    int d = ei[e];
    int p = atomicAdd(&cur[d], 1);
    eids[p] = e;
  }
}

__global__ __launch_bounds__(256) void k_h(const float* __restrict__ ee,
                                           const float* __restrict__ Wf1,
                                           float* __restrict__ h, int nedges) {
  __shared__ float s_w[64];
  const int tid = threadIdx.x;
  if (tid < 64) s_w[tid] = Wf1[tid];
  __syncthreads();
  int e = blockIdx.x * 256 + tid;
  if (e >= nedges) return;
  const float4 a = *(const float4*)(ee + (size_t)e * 8);
  const float4 b = *(const float4*)(ee + (size_t)e * 8 + 4);
  float r[8];
  const float is8 = 0.35355339059327379f;  // 1/sqrt(8)
#pragma unroll
  for (int j = 0; j < 8; ++j) {
    float d = a.x * s_w[0 * 8 + j] + a.y * s_w[1 * 8 + j] + a.z * s_w[2 * 8 + j] +
              a.w * s_w[3 * 8 + j] + b.x * s_w[4 * 8 + j] + b.y * s_w[5 * 8 + j] +
              b.z * s_w[6 * 8 + j] + b.w * s_w[7 * 8 + j];
    d *= is8;                                         // /sqrt(NB) before softplus
    float sp = fmaxf(d, 0.f) + log1pf(__expf(-fabsf(d)));
    r[j] = (sp - 0.69314718055994531f) * is8;         // -ln2, fold /sqrt(H) of w
  }
  *(float4*)(h + (size_t)e * 8) = make_float4(r[0], r[1], r[2], r[3]);
  *(float4*)(h + (size_t)e * 8 + 4) = make_float4(r[4], r[5], r[6], r[7]);
}

// 16 nodes per block (4 per wave), lane = output column v.
__global__ __launch_bounds__(256) void k_node_pre(
    const float* __restrict__ nf, const float* __restrict__ na,
    const float* __restrict__ W10, const float* __restrict__ W11,
    const float* __restrict__ Ws0, const float* __restrict__ Ws1,
    float* __restrict__ y, float* __restrict__ out, int nnodes) {
  __shared__ float s_nf[16][256];
  __shared__ float s_na[16][4];
  const int tid = threadIdx.x;
  const int lane = tid & 63;
  const int wv = tid >> 6;
  const int base = blockIdx.x * 16;

  for (int i = tid; i < 16 * 256; i += 256) {
    int r = i >> 8, c = i & 255;
    int n = base + r;
    s_nf[r][c] = (n < nnodes) ? nf[(size_t)n * 256 + c] : 0.f;
  }
  if (tid < 64) {
    int r = tid >> 2, c = tid & 3;
    int n = base + r;
    s_na[r][c] = (n < nnodes) ? na[(size_t)n * 4 + c] : 0.f;
  }
  __syncthreads();

  const int r0 = wv * 4;
  const int v = lane;
  float y0a[4] = {0.f, 0.f, 0.f, 0.f};
  float y1a[4][3] = {};
  float sc0a[4] = {0.f, 0.f, 0.f, 0.f};
  float sc1a[4][3] = {};

  for (int u = 0; u < 64; ++u) {
    const float w0 = W10[u * 64 + v];
    const float w1 = W11[u * 64 + v];
#pragma unroll
    for (int r = 0; r < 4; ++r) {
      y0a[r] = fmaf(s_nf[r0 + r][u], w0, y0a[r]);
#pragma unroll
      for (int m = 0; m < 3; ++m)
        y1a[r][m] = fmaf(s_nf[r0 + r][64 + u * 3 + m], w1, y1a[r][m]);
    }
  }

  for (int u = 0; u < 64; ++u) {
    float x0r[4], x1r[4][3];
#pragma unroll
    for (int r = 0; r < 4; ++r) {
      x0r[r] = s_nf[r0 + r][u];
#pragma unroll
      for (int m = 0; m < 3; ++m) x1r[r][m] = s_nf[r0 + r][64 + u * 3 + m];
    }
#pragma unroll
    for (int a = 0; a < 4; ++a) {
      const float w0 = Ws0[u * 256 + a * 64 + v];
      const float w1 = Ws1[u * 256 + a * 64 + v];
#pragma unroll
      for (int r = 0; r < 4; ++r) {
        const float nav = s_na[r0 + r][a];
        sc0a[r] = fmaf(x0r[r] * nav, w0, sc0a[r]);
        const float t = nav * w1;
#pragma unroll
        for (int m = 0; m < 3; ++m)
          sc1a[r][m] = fmaf(x1r[r][m], t, sc1a[r][m]);
      }
    }
  }

#pragma unroll
  for (int r = 0; r < 4; ++r) {
    const int n = base + r0 + r;
    if (n < nnodes) {
      y[(size_t)n * 256 + v] = y0a[r] * 0.125f;          // /sqrt(C)
      out[(size_t)n * 256 + v] = sc0a[r] * 0.0625f;      // /sqrt(C*A)
#pragma unroll
      for (int m = 0; m < 3; ++m) {
        y[(size_t)n * 256 + 64 + v * 3 + m] = y1a[r][m] * 0.125f;
        out[(size_t)n * 256 + 64 + v * 3 + m] = sc1a[r][m] * 0.0625f;
      }
    }
  }
}

// One node per block-iteration; 4 waves split the edge list; lane = u.
__global__ __launch_bounds__(256) void k_agg(
    const float* __restrict__ y, const float* __restrict__ h,
    const float* __restrict__ ea, const int* __restrict__ ei,
    const int* __restrict__ offs, const int* __restrict__ eids,
    const float* __restrict__ Wf2, const float* __restrict__ W20,
    const float* __restrict__ W21, float* __restrict__ out,
    int nnodes, int nedges) {
  __shared__ float s_fc2[2048];
  __shared__ float s_part[4][512];
  __shared__ float s_fin[512];
  const int tid = threadIdx.x;
  const int lane = tid & 63;
  const int wv = tid >> 6;
  for (int i = tid; i < 2048; i += 256) s_fc2[i] = Wf2[i];

  for (int n = blockIdx.x; n < nnodes; n += gridDim.x) {
    __syncthreads();  // covers fc2 staging (iter 0) and s_part reuse across iters
    const int beg = offs[n], end = offs[n + 1];
    const int u = lane;
    float as0 = 0.f, as1 = 0.f;
    float av0[3] = {0.f, 0.f, 0.f};
    float av1[3] = {0.f, 0.f, 0.f};
    for (int i = beg + wv; i < end; i += 4) {
      const int e = eids[i];
      const int src = ei[nedges + e];  // row 1 = src
      const float* hp = h + (size_t)e * 8;
      float hv[8];
#pragma unroll
      for (int k = 0; k < 8; ++k) hv[k] = hp[k];
      const float4 sh = *(const float4*)(ea + (size_t)e * 4);  // x=sh0, yzw=sh1
      float wp1 = 0.f, wp2 = 0.f, wp3 = 0.f, wp4 = 0.f;
#pragma unroll
      for (int k = 0; k < 8; ++k) {
        wp1 = fmaf(hv[k], s_fc2[k * 256 + u], wp1);
        wp2 = fmaf(hv[k], s_fc2[k * 256 + 64 + u], wp2);
        wp3 = fmaf(hv[k], s_fc2[k * 256 + 128 + u], wp3);
        wp4 = fmaf(hv[k], s_fc2[k * 256 + 192 + u], wp4);
      }
      const float* yr = y + (size_t)src * 256;
      const float xs0 = yr[u];
      const float x1a = yr[64 + u * 3];
      const float x1b = yr[64 + u * 3 + 1];
      const float x1c = yr[64 + u * 3 + 2];
      const float dot3 = x1a * sh.y + x1b * sh.z + x1c * sh.w;
      as0 = fmaf(wp1 * xs0, sh.x, as0);
      as1 = fmaf(wp4, dot3, as1);
      const float t2 = wp2 * xs0;
      av0[0] = fmaf(t2, sh.y, av0[0]);
      av0[1] = fmaf(t2, sh.z, av0[1]);
      av0[2] = fmaf(t2, sh.w, av0[2]);
      const float t3 = wp3 * sh.x;
      av1[0] = fmaf(t3, x1a, av1[0]);
      av1[1] = fmaf(t3, x1b, av1[1]);
      av1[2] = fmaf(t3, x1c, av1[2]);
    }
    s_part[wv][u] = as0;
    s_part[wv][64 + u] = as1 * 0.57735026918962576f;  // /sqrt(3)
#pragma unroll
    for (int m = 0; m < 3; ++m) {
      s_part[wv][128 + u * 3 + m] = av0[m];
      s_part[wv][320 + u * 3 + m] = av1[m];
    }
    __syncthreads();
    for (int j = tid; j < 512; j += 256)
      s_fin[j] = s_part[0][j] + s_part[1][j] + s_part[2][j] + s_part[3][j];
    __syncthreads();
    const float scl = 1.f / 64.f;  // 1/sqrt(32) * 1/sqrt(128)
    if (wv == 0) {
      float acc = 0.f;
      for (int up = 0; up < 128; ++up)
        acc = fmaf(s_fin[up], W20[up * 64 + lane], acc);
      out[(size_t)n * 256 + lane] += acc * scl;
    } else {
      const int m = wv - 1;
      float acc = 0.f;
      for (int up = 0; up < 128; ++up)
        acc = fmaf(s_fin[128 + up * 3 + m], W21[up * 64 + lane], acc);
      out[(size_t)n * 256 + 64 + lane * 3 + m] += acc * scl;
    }
  }
}

extern "C" void kernel_launch(void* const* d_in, const int* in_sizes, int n_in,
                              void* d_out, int out_size, void* d_ws, size_t ws_size,
                              hipStream_t stream) {
  const float* nf = (const float*)d_in[0];
  const float* na = (const float*)d_in[1];
  const float* ea = (const float*)d_in[2];
  const float* ee = (const float*)d_in[3];
  const int* ei = (const int*)d_in[4];
  const float* W10 = (const float*)d_in[5];
  const float* W11 = (const float*)d_in[6];
  const float* Wf1 = (const float*)d_in[7];
  const float* Wf2 = (const float*)d_in[8];
  const float* W20 = (const float*)d_in[9];
  const float* W21 = (const float*)d_in[10];
  const float* Ws0 = (const float*)d_in[11];
  const float* Ws1 = (const float*)d_in[12];
  float* out = (float*)d_out;

  const int N = in_sizes[1] / 4;  // node_attrs is N x 4
  const int E = in_sizes[2] / 4;  // edge_attrs is E x 4

  char* w = (char*)d_ws;
  auto carve = [&](size_t bytes) {
    char* p = w;
    w += (bytes + 255) & ~(size_t)255;
    return p;
  };
  float* yb = (float*)carve((size_t)N * 256 * sizeof(float));   // 10.24 MB
  float* hb = (float*)carve((size_t)E * 8 * sizeof(float));     // 10.24 MB
  int* cnt = (int*)carve((size_t)N * sizeof(int));
  int* offs = (int*)carve((size_t)(N + 1) * sizeof(int));
  int* cur = (int*)carve((size_t)N * sizeof(int));
  int* eids = (int*)carve((size_t)E * sizeof(int));             // 1.28 MB

  hipMemsetAsync(cnt, 0, (size_t)N * sizeof(int), stream);
  const int egrid = (E + 255) / 256;
  k_hist<<<egrid, 256, 0, stream>>>(ei, cnt, E);
  k_scan<<<1, 1024, 0, stream>>>(cnt, offs, cur, N, E);
  k_scatter<<<egrid, 256, 0, stream>>>(ei, cur, eids, E);
  k_h<<<egrid, 256, 0, stream>>>(ee, Wf1, hb, E);
  k_node_pre<<<(N + 15) / 16, 256, 0, stream>>>(nf, na, W10, W11, Ws0, Ws1, yb, out, N);
  const int agrid = (N < 2500) ? N : 2500;
  k_agg<<<agrid, 256, 0, stream>>>(yb, hb, ea, ei, offs, eids, Wf2, W20, W21, out, N, E);
}

// Round 2
// 296.740 us; speedup vs baseline: 1.1760x; 1.1760x over previous
//
#include <hip/hip_runtime.h>

// InteractionBlock: N=10000, E=320000, C=64, A=4, NB=8, H=8.
// Pipeline:
//   memset cnt -> k_hist -> k_scan -> k_scatter (CSR by dst; srcs[] + pos[])
//   k_h        : h=(softplus(ee@Wfc1/sqrt8)-ln2)/sqrt8, write CSR-ordered
//                12-float records {h[8], sh0, sh1[3]} at ehw[pos[e]]
//   k_node_pre : yq rows [n][u][4]={y0,y1m0..2} (lin1, /8) -> ws; sc (/16) -> out
//   k_agg      : wave-per-node gather; W_fc2 in registers; single float4 y load
//                per edge; LDS exchange; out += (agg @ Wlin2)/64

__global__ __launch_bounds__(256) void k_hist(const int* __restrict__ ei,
                                              int* __restrict__ cnt, int nedges) {
  int e = blockIdx.x * 256 + threadIdx.x;
  if (e < nedges) atomicAdd(&cnt[ei[e]], 1);  // row 0 = dst
}

__global__ __launch_bounds__(1024) void k_scan(const int* __restrict__ cnt,
                                               int* __restrict__ offs,
                                               int* __restrict__ cur,
                                               int nnodes, int nedges) {
  __shared__ int s[1024];
  const int tid = threadIdx.x;
  int vals[16];
  int tot = 0;
  const int start = tid * 16;
#pragma unroll
  for (int k = 0; k < 16; ++k) {
    int i = start + k;
    int c = (i < nnodes) ? cnt[i] : 0;
    vals[k] = c;
    tot += c;
  }
  s[tid] = tot;
  __syncthreads();
  for (int off = 1; off < 1024; off <<= 1) {
    int v = (tid >= off) ? s[tid - off] : 0;
    __syncthreads();
    s[tid] += v;
    __syncthreads();
  }
  int run = s[tid] - tot;
#pragma unroll
  for (int k = 0; k < 16; ++k) {
    int i = start + k;
    if (i < nnodes) {
      offs[i] = run;
      cur[i] = run;
      run += vals[k];
    }
  }
  if (tid == 0) offs[nnodes] = nedges;
}

__global__ __launch_bounds__(256) void k_scatter(const int* __restrict__ ei,
                                                 int* __restrict__ cur,
                                                 int* __restrict__ srcs,
                                                 int* __restrict__ pos, int nedges) {
  int e = blockIdx.x * 256 + threadIdx.x;
  if (e < nedges) {
    int d = ei[e];
    int s = ei[nedges + e];
    int p = atomicAdd(&cur[d], 1);
    srcs[p] = s;
    pos[e] = p;
  }
}

__global__ __launch_bounds__(256) void k_h(const float* __restrict__ ee,
                                           const float* __restrict__ Wf1,
                                           const float* __restrict__ ea,
                                           const int* __restrict__ pos,
                                           float* __restrict__ ehw, int nedges) {
  __shared__ float s_w[64];
  const int tid = threadIdx.x;
  if (tid < 64) s_w[tid] = Wf1[tid];
  __syncthreads();
  int e = blockIdx.x * 256 + tid;
  if (e >= nedges) return;
  const float4 a = *(const float4*)(ee + (size_t)e * 8);
  const float4 b = *(const float4*)(ee + (size_t)e * 8 + 4);
  float r[8];
  const float is8 = 0.35355339059327379f;  // 1/sqrt(8)
#pragma unroll
  for (int j = 0; j < 8; ++j) {
    float d = a.x * s_w[0 * 8 + j] + a.y * s_w[1 * 8 + j] + a.z * s_w[2 * 8 + j] +
              a.w * s_w[3 * 8 + j] + b.x * s_w[4 * 8 + j] + b.y * s_w[5 * 8 + j] +
              b.z * s_w[6 * 8 + j] + b.w * s_w[7 * 8 + j];
    d *= is8;                                         // /sqrt(NB)
    float sp = fmaxf(d, 0.f) + log1pf(__expf(-fabsf(d)));
    r[j] = (sp - 0.69314718055994531f) * is8;         // -ln2, fold /sqrt(H)
  }
  const size_t p = (size_t)pos[e] * 12;
  *(float4*)(ehw + p) = make_float4(r[0], r[1], r[2], r[3]);
  *(float4*)(ehw + p + 4) = make_float4(r[4], r[5], r[6], r[7]);
  *(float4*)(ehw + p + 8) = *(const float4*)(ea + (size_t)e * 4);  // sh0, sh1
}

// 16 nodes per block (4 per wave), lane = output column v.
__global__ __launch_bounds__(256) void k_node_pre(
    const float* __restrict__ nf, const float* __restrict__ na,
    const float* __restrict__ W10, const float* __restrict__ W11,
    const float* __restrict__ Ws0, const float* __restrict__ Ws1,
    float* __restrict__ yq, float* __restrict__ out, int nnodes) {
  __shared__ float s_nf[16][256];
  __shared__ float s_na[16][4];
  const int tid = threadIdx.x;
  const int lane = tid & 63;
  const int wv = tid >> 6;
  const int base = blockIdx.x * 16;

  for (int i = tid; i < 16 * 256; i += 256) {
    int r = i >> 8, c = i & 255;
    int n = base + r;
    s_nf[r][c] = (n < nnodes) ? nf[(size_t)n * 256 + c] : 0.f;
  }
  if (tid < 64) {
    int r = tid >> 2, c = tid & 3;
    int n = base + r;
    s_na[r][c] = (n < nnodes) ? na[(size_t)n * 4 + c] : 0.f;
  }
  __syncthreads();

  const int r0 = wv * 4;
  const int v = lane;
  float y0a[4] = {0.f, 0.f, 0.f, 0.f};
  float y1a[4][3] = {};
  float sc0a[4] = {0.f, 0.f, 0.f, 0.f};
  float sc1a[4][3] = {};

#pragma unroll 4
  for (int u = 0; u < 64; ++u) {
    float x0r[4], x1r[4][3];
#pragma unroll
    for (int r = 0; r < 4; ++r) {
      x0r[r] = s_nf[r0 + r][u];
#pragma unroll
      for (int m = 0; m < 3; ++m) x1r[r][m] = s_nf[r0 + r][64 + u * 3 + m];
    }
    const float w0 = W10[u * 64 + v];
    const float w1 = W11[u * 64 + v];
#pragma unroll
    for (int r = 0; r < 4; ++r) {
      y0a[r] = fmaf(x0r[r], w0, y0a[r]);
#pragma unroll
      for (int m = 0; m < 3; ++m) y1a[r][m] = fmaf(x1r[r][m], w1, y1a[r][m]);
    }
#pragma unroll
    for (int a = 0; a < 4; ++a) {
      const float ws0 = Ws0[u * 256 + a * 64 + v];
      const float ws1 = Ws1[u * 256 + a * 64 + v];
#pragma unroll
      for (int r = 0; r < 4; ++r) {
        const float nav = s_na[r0 + r][a];
        sc0a[r] = fmaf(x0r[r] * nav, ws0, sc0a[r]);
        const float t = nav * ws1;
#pragma unroll
        for (int m = 0; m < 3; ++m)
          sc1a[r][m] = fmaf(x1r[r][m], t, sc1a[r][m]);
      }
    }
  }

#pragma unroll
  for (int r = 0; r < 4; ++r) {
    const int n = base + r0 + r;
    if (n < nnodes) {
      *(float4*)(yq + ((size_t)n * 64 + v) * 4) =
          make_float4(y0a[r] * 0.125f, y1a[r][0] * 0.125f,
                      y1a[r][1] * 0.125f, y1a[r][2] * 0.125f);  // /sqrt(C)
      out[(size_t)n * 256 + v] = sc0a[r] * 0.0625f;             // /sqrt(C*A)
#pragma unroll
      for (int m = 0; m < 3; ++m)
        out[(size_t)n * 256 + 64 + v * 3 + m] = sc1a[r][m] * 0.0625f;
    }
  }
}

// One node per WAVE; lane = channel u. W_fc2 columns live in registers.
__global__ __launch_bounds__(256, 4) void k_agg(
    const float* __restrict__ yq, const float* __restrict__ ehw,
    const int* __restrict__ srcs, const int* __restrict__ offs,
    const float* __restrict__ Wf2, const float* __restrict__ W20,
    const float* __restrict__ W21, float* __restrict__ out, int nnodes) {
  __shared__ float s_x[4][512];
  const int tid = threadIdx.x;
  const int u = tid & 63;
  const int wv = tid >> 6;
  const int n = blockIdx.x * 4 + wv;

  float wreg[32];
#pragma unroll
  for (int j = 0; j < 8; ++j)
#pragma unroll
    for (int q = 0; q < 4; ++q) wreg[j * 4 + q] = Wf2[j * 256 + q * 64 + u];

  float as0 = 0.f, as1 = 0.f;
  float av0[3] = {0.f, 0.f, 0.f};
  float av1[3] = {0.f, 0.f, 0.f};

  if (n < nnodes) {
    const int beg = offs[n], end = offs[n + 1];
#pragma unroll 4
    for (int i = beg; i < end; ++i) {
      const int src = srcs[i];
      const float4 yv = *(const float4*)(yq + ((size_t)src * 64 + u) * 4);
      const float4 h0 = *(const float4*)(ehw + (size_t)i * 12);
      const float4 h1 = *(const float4*)(ehw + (size_t)i * 12 + 4);
      const float4 sh = *(const float4*)(ehw + (size_t)i * 12 + 8);
      const float hv[8] = {h0.x, h0.y, h0.z, h0.w, h1.x, h1.y, h1.z, h1.w};
      float wp[4] = {0.f, 0.f, 0.f, 0.f};
#pragma unroll
      for (int j = 0; j < 8; ++j)
#pragma unroll
        for (int q = 0; q < 4; ++q) wp[q] = fmaf(hv[j], wreg[j * 4 + q], wp[q]);
      const float dot3 = yv.y * sh.y + yv.z * sh.z + yv.w * sh.w;
      as0 = fmaf(wp[0] * yv.x, sh.x, as0);
      as1 = fmaf(wp[3], dot3, as1);
      const float t2 = wp[1] * yv.x;
      av0[0] = fmaf(t2, sh.y, av0[0]);
      av0[1] = fmaf(t2, sh.z, av0[1]);
      av0[2] = fmaf(t2, sh.w, av0[2]);
      const float t3 = wp[2] * sh.x;
      av1[0] = fmaf(t3, yv.y, av1[0]);
      av1[1] = fmaf(t3, yv.z, av1[1]);
      av1[2] = fmaf(t3, yv.w, av1[2]);
    }
  }

  s_x[wv][u] = as0;
  s_x[wv][64 + u] = as1 * 0.57735026918962576f;  // /sqrt(3)
#pragma unroll
  for (int m = 0; m < 3; ++m) {
    s_x[wv][128 + m * 64 + u] = av0[m];
    s_x[wv][320 + m * 64 + u] = av1[m];
  }
  __syncthreads();

  if (n < nnodes) {
    const float scl = 1.f / 64.f;  // 1/sqrt(32) * 1/sqrt(128)
    float o0 = 0.f;
#pragma unroll 8
    for (int up = 0; up < 128; up += 4) {
      const float4 sv = *(const float4*)&s_x[wv][up];
      o0 = fmaf(sv.x, W20[(up + 0) * 64 + u], o0);
      o0 = fmaf(sv.y, W20[(up + 1) * 64 + u], o0);
      o0 = fmaf(sv.z, W20[(up + 2) * 64 + u], o0);
      o0 = fmaf(sv.w, W20[(up + 3) * 64 + u], o0);
    }
    out[(size_t)n * 256 + u] += o0 * scl;
#pragma unroll
    for (int m = 0; m < 3; ++m) {
      float acc = 0.f;
#pragma unroll 8
      for (int up = 0; up < 64; up += 4) {
        const float4 a = *(const float4*)&s_x[wv][128 + m * 64 + up];
        acc = fmaf(a.x, W21[(up + 0) * 64 + u], acc);
        acc = fmaf(a.y, W21[(up + 1) * 64 + u], acc);
        acc = fmaf(a.z, W21[(up + 2) * 64 + u], acc);
        acc = fmaf(a.w, W21[(up + 3) * 64 + u], acc);
      }
#pragma unroll 8
      for (int up = 0; up < 64; up += 4) {
        const float4 b = *(const float4*)&s_x[wv][320 + m * 64 + up];
        acc = fmaf(b.x, W21[(64 + up + 0) * 64 + u], acc);
        acc = fmaf(b.y, W21[(64 + up + 1) * 64 + u], acc);
        acc = fmaf(b.z, W21[(64 + up + 2) * 64 + u], acc);
        acc = fmaf(b.w, W21[(64 + up + 3) * 64 + u], acc);
      }
      out[(size_t)n * 256 + 64 + u * 3 + m] += acc * scl;
    }
  }
}

extern "C" void kernel_launch(void* const* d_in, const int* in_sizes, int n_in,
                              void* d_out, int out_size, void* d_ws, size_t ws_size,
                              hipStream_t stream) {
  const float* nf = (const float*)d_in[0];
  const float* na = (const float*)d_in[1];
  const float* ea = (const float*)d_in[2];
  const float* ee = (const float*)d_in[3];
  const int* ei = (const int*)d_in[4];
  const float* W10 = (const float*)d_in[5];
  const float* W11 = (const float*)d_in[6];
  const float* Wf1 = (const float*)d_in[7];
  const float* Wf2 = (const float*)d_in[8];
  const float* W20 = (const float*)d_in[9];
  const float* W21 = (const float*)d_in[10];
  const float* Ws0 = (const float*)d_in[11];
  const float* Ws1 = (const float*)d_in[12];
  float* out = (float*)d_out;

  const int N = in_sizes[1] / 4;  // node_attrs is N x 4
  const int E = in_sizes[2] / 4;  // edge_attrs is E x 4

  char* w = (char*)d_ws;
  auto carve = [&](size_t bytes) {
    char* p = w;
    w += (bytes + 255) & ~(size_t)255;
    return p;
  };
  float* yq = (float*)carve((size_t)N * 256 * sizeof(float));   // 10.24 MB
  float* ehw = (float*)carve((size_t)E * 12 * sizeof(float));   // 15.36 MB
  int* cnt = (int*)carve((size_t)N * sizeof(int));
  int* offs = (int*)carve((size_t)(N + 1) * sizeof(int));
  int* cur = (int*)carve((size_t)N * sizeof(int));
  int* srcs = (int*)carve((size_t)E * sizeof(int));             // 1.28 MB
  int* pos = (int*)carve((size_t)E * sizeof(int));              // 1.28 MB

  hipMemsetAsync(cnt, 0, (size_t)N * sizeof(int), stream);
  const int egrid = (E + 255) / 256;
  k_hist<<<egrid, 256, 0, stream>>>(ei, cnt, E);
  k_scan<<<1, 1024, 0, stream>>>(cnt, offs, cur, N, E);
  k_scatter<<<egrid, 256, 0, stream>>>(ei, cur, srcs, pos, E);
  k_h<<<egrid, 256, 0, stream>>>(ee, Wf1, ea, pos, ehw, E);
  k_node_pre<<<(N + 15) / 16, 256, 0, stream>>>(nf, na, W10, W11, Ws0, Ws1, yq, out, N);
  k_agg<<<(N + 3) / 4, 256, 0, stream>>>(yq, ehw, srcs, offs, Wf2, W20, W21, out, N);
}